// Round 12
// baseline (751.472 us; speedup 1.0000x reference)
//
#include <hip/hip_runtime.h>

#define N_ROWS 8192
#define DIM    512

typedef __attribute__((ext_vector_type(4))) float frag_cd;      // 4 fp32 acc
typedef __attribute__((ext_vector_type(2))) long long v2ll;     // 16B = 2 fp8 fragments

// fp32 -> OCP e4m3fn, RNE, FTZ below 2^-6 (negligible for N(0,1) data).
__device__ __forceinline__ unsigned f2fp8(float x) {
    float a = fabsf(x);
    unsigned s = (__float_as_uint(x) >> 31) << 7;
    if (a < 0.015625f) return s;                 // FTZ subnormals
    a = fminf(a, 448.f);                         // e4m3fn max
    unsigned u = __float_as_uint(a);
    u += 0x7FFFFu + ((u >> 20) & 1u);            // RNE round mantissa to 3 bits
    unsigned exp = (u >> 23) - 120u;             // fp32exp-127+7 in [1,15]
    unsigned mant = (u >> 20) & 7u;
    return s | (exp << 3) | mant;
}
__device__ __forceinline__ unsigned pack4fp8(float4 v) {
    return f2fp8(v.x) | (f2fp8(v.y) << 8) | (f2fp8(v.z) << 16) | (f2fp8(v.w) << 24);
}
// order-preserving f32 -> u32 key (monotone), so atomicMax(uint) == float max
__device__ __forceinline__ unsigned enc_f32(float f) {
    unsigned u = __float_as_uint(f);
    return (u & 0x80000000u) ? ~u : (u | 0x80000000u);
}
__device__ __forceinline__ float dec_f32(unsigned k) {
    return __uint_as_float((k & 0x80000000u) ? (k & 0x7FFFFFFFu) : ~k);
}

// ---- TILED fp8 layout (round-8/9/10 verified exact) ----
// Pair-chunk (cr, kp) = 16 rows x 64 K-cols = 1 KB, 64 units of 16B:
// unit u = cg*16+rin = [kc-even 8B | kc-odd 8B], cols kp*64+par*32+cg*8.
// Byte addr = cr*8192 + kp*1024 + u*16.

// ---- kernel 1: convert + diag + init (round-10 verbatim + zero done ctr) ----
__global__ __launch_bounds__(256) void k_prep(const float* __restrict__ imgs,
                                              const float* __restrict__ caps,
                                              unsigned char* __restrict__ fimgs,
                                              unsigned char* __restrict__ fcaps,
                                              float* __restrict__ diag,
                                              unsigned* __restrict__ rowmax,
                                              unsigned* __restrict__ colmax,
                                              unsigned* __restrict__ done,
                                              float* __restrict__ out) {
    const int cr = blockIdx.x;            // 0..511
    const int t  = threadIdx.x;
    const int w = t >> 6, l = t & 63;
    const int kp = l >> 3, cg = l & 3, par = (l >> 2) & 1;
    if (cr == 0 && t == 0) { out[0] = 0.f; done[0] = 0u; }
    // lane's 8 cols = kp*64 + par*32 + cg*8 .. +7  == cols l*8..l*8+7
    const size_t ubase = (size_t)cr * 8192 + kp * 1024 + cg * 256 + par * 8;
    float ps[4];
    #pragma unroll
    for (int i = 0; i < 4; ++i) {
        const int row = w + 4 * i;                 // 0..15
        const float* ar = imgs + ((size_t)cr * 16 + row) * DIM + l * 8;
        const float* br = caps + ((size_t)cr * 16 + row) * DIM + l * 8;
        float4 a0 = *(const float4*)ar, a1 = *(const float4*)(ar + 4);
        float4 b0 = *(const float4*)br, b1 = *(const float4*)(br + 4);
        uint2 oa, ob;
        oa.x = pack4fp8(a0); oa.y = pack4fp8(a1);
        ob.x = pack4fp8(b0); ob.y = pack4fp8(b1);
        *(uint2*)(fimgs + ubase + row * 16) = oa;
        *(uint2*)(fcaps + ubase + row * 16) = ob;
        ps[i] = a0.x * b0.x + a0.y * b0.y + a0.z * b0.z + a0.w * b0.w
              + a1.x * b1.x + a1.y * b1.y + a1.z * b1.z + a1.w * b1.w;
    }
    #pragma unroll
    for (int i = 0; i < 4; ++i) {
        float s = ps[i];
        #pragma unroll
        for (int m = 1; m < 64; m <<= 1) s += __shfl_xor(s, m, 64);
        if (l == 0) {
            const int r = cr * 16 + w + 4 * i;
            diag[r] = s; rowmax[r] = 0u; colmax[r] = 0u;
        }
    }
}

// ---- kernel 2: fused fp8 NT-GEMM + diag flip + row/col max + last-block final ----
// Round-10 body verbatim; appended tail: threadfence + done-counter, the
// 8192nd block performs the hinge reduction (saves the k_final launch).
__global__ __launch_bounds__(256, 6) void k_gemm(const unsigned char* __restrict__ A,
                                                 const unsigned char* __restrict__ B,
                                                 unsigned* __restrict__ rowmax,
                                                 unsigned* __restrict__ colmax,
                                                 const float* __restrict__ diag,
                                                 unsigned* __restrict__ done,
                                                 float* __restrict__ out) {
    __shared__ unsigned char sA[2][4096];   // 4 chunk slots x 1 KB
    __shared__ unsigned char sB[2][8192];   // 8 chunk slots x 1 KB
    const int tid = threadIdx.x;
    const int w = tid >> 6, lane = tid & 63;
    const int j0 = (int)blockIdx.x << 7, i0 = (int)blockIdx.y << 6;
    const int q = lane >> 4, l15 = lane & 15;
    const int wr = (w & 1) << 5, wc = (w >> 1) << 6;   // wave tile origin

    const unsigned char* Ab = A + (size_t)(i0 >> 4) * 8192 + lane * 16;
    const unsigned char* Bb = B + (size_t)(j0 >> 4) * 8192 + lane * 16;

    frag_cd acc[2][4] = {};

    auto stage = [&](int bi, int kp) {
        __builtin_amdgcn_global_load_lds(
            (const __attribute__((address_space(1))) unsigned int*)(Ab + (size_t)w * 8192 + kp * 1024),
            (__attribute__((address_space(3))) unsigned int*)(&sA[bi][(w << 10) + (lane << 4)]), 16, 0, 0);
        #pragma unroll
        for (int j = 0; j < 2; ++j) {
            const int s = 2 * w + j;
            __builtin_amdgcn_global_load_lds(
                (const __attribute__((address_space(1))) unsigned int*)(Bb + (size_t)s * 8192 + kp * 1024),
                (__attribute__((address_space(3))) unsigned int*)(&sB[bi][(s << 10) + (lane << 4)]), 16, 0, 0);
        }
    };

    stage(0, 0);
    __syncthreads();   // cold drain (once)

    const int u16 = ((q << 4) + l15) << 4;   // fragment byte offset in chunk

    #pragma unroll
    for (int kp = 0; kp < 8; ++kp) {
        const int cur = kp & 1, nxt = cur ^ 1;
        if (kp < 7) stage(nxt, kp + 1);   // in flight during compute below

        v2ll af[2], bfr[4];
        #pragma unroll
        for (int r = 0; r < 2; ++r)   // A chunk = (w&1)*2 + r
            af[r] = *(const v2ll*)(&sA[cur][((((w & 1) << 1) + r) << 10) + u16]);
        #pragma unroll
        for (int c = 0; c < 4; ++c)   // B chunk = (w>>1)*4 + c
            bfr[c] = *(const v2ll*)(&sB[cur][((((w >> 1) << 2) + c) << 10) + u16]);
        #pragma unroll
        for (int r = 0; r < 2; ++r)
            #pragma unroll
            for (int c = 0; c < 4; ++c)
                acc[r][c] = __builtin_amdgcn_mfma_f32_16x16x32_fp8_fp8(af[r][0], bfr[c][0], acc[r][c], 0, 0, 0);
        #pragma unroll
        for (int r = 0; r < 2; ++r)
            #pragma unroll
            for (int c = 0; c < 4; ++c)
                acc[r][c] = __builtin_amdgcn_mfma_f32_16x16x32_fp8_fp8(af[r][1], bfr[c][1], acc[r][c], 0, 0, 0);

        __syncthreads();
    }

    // ---- epilogue: diagonal flip + row/col max + device atomics ----
    // C/D layout: col = lane&15, row = (lane>>4)*4 + reg (dtype-independent)
    const bool dblk = ((i0 >> 7) == (int)blockIdx.x);
    #pragma unroll
    for (int r = 0; r < 2; ++r)
        #pragma unroll
        for (int c = 0; c < 4; ++c)
            #pragma unroll
            for (int g = 0; g < 4; ++g) {
                float f = acc[r][c][g];
                const int gi = wr + (r << 4) + (q << 2) + g;          // row in block
                const int gj = wc + (c << 4) + l15;                   // col in block
                if (dblk && (i0 + gi) == (j0 + gj)) f = -f;           // s[i][i] = -diag
                acc[r][c][g] = f;
            }

    #pragma unroll
    for (int r = 0; r < 2; ++r)
        #pragma unroll
        for (int g = 0; g < 4; ++g) {
            float m = fmaxf(fmaxf(acc[r][0][g], acc[r][1][g]),
                            fmaxf(acc[r][2][g], acc[r][3][g]));
            m = fmaxf(m, __shfl_xor(m, 1, 64));
            m = fmaxf(m, __shfl_xor(m, 2, 64));
            m = fmaxf(m, __shfl_xor(m, 4, 64));
            m = fmaxf(m, __shfl_xor(m, 8, 64));
            if (l15 == 0)
                atomicMax(&rowmax[i0 + wr + (r << 4) + (q << 2) + g], enc_f32(m));
        }
    #pragma unroll
    for (int c = 0; c < 4; ++c) {
        float m = acc[0][c][0];
        #pragma unroll
        for (int r = 0; r < 2; ++r)
            #pragma unroll
            for (int g = 0; g < 4; ++g) m = fmaxf(m, acc[r][c][g]);
        m = fmaxf(m, __shfl_xor(m, 16, 64));
        m = fmaxf(m, __shfl_xor(m, 32, 64));
        if (q == 0)
            atomicMax(&colmax[j0 + wc + (c << 4) + l15], enc_f32(m));
    }

    // ---- last-block final reduction (replaces k_final launch) ----
    __threadfence();   // make this block's atomicMax results device-visible
    __shared__ unsigned lastflag;
    __shared__ float red[4];
    if (tid == 0)
        lastflag = (atomicAdd(done, 1u) == 8191u) ? 1u : 0u;
    __syncthreads();
    if (lastflag) {
        float s = 0.f;
        #pragma unroll
        for (int i = 0; i < 32; ++i) {
            const int idx = tid + (i << 8);
            // AGENT-scope atomic loads: bypass potentially-stale per-XCD cache
            const unsigned rk = __hip_atomic_load(&rowmax[idx], __ATOMIC_RELAXED, __HIP_MEMORY_SCOPE_AGENT);
            const unsigned ck = __hip_atomic_load(&colmax[idx], __ATOMIC_RELAXED, __HIP_MEMORY_SCOPE_AGENT);
            const float d = diag[idx];
            s += fmaxf(dec_f32(rk) + 0.2f - d, 0.f)    // neg_img
               + fmaxf(dec_f32(ck) + 0.2f - d, 0.f);   // neg_cap
        }
        #pragma unroll
        for (int m = 1; m < 64; m <<= 1) s += __shfl_xor(s, m, 64);
        if ((tid & 63) == 0) red[tid >> 6] = s;
        __syncthreads();
        if (tid == 0) out[0] = red[0] + red[1] + red[2] + red[3];
    }
}

extern "C" void kernel_launch(void* const* d_in, const int* in_sizes, int n_in,
                              void* d_out, int out_size, void* d_ws, size_t ws_size,
                              hipStream_t stream) {
    const float* imgs = (const float*)d_in[0];
    const float* caps = (const float*)d_in[1];
    float* out = (float*)d_out;

    char* ws = (char*)d_ws;
    unsigned char* fimgs = (unsigned char*)ws;                         // 4 MB tiled fp8
    unsigned char* fcaps = (unsigned char*)(ws + 4194304);             // 4 MB tiled fp8
    float*    diag   = (float*)   (ws + 8388608);                      // 32 KB
    unsigned* rowmax = (unsigned*)(ws + 8388608 + 32768);              // 32 KB
    unsigned* colmax = (unsigned*)(ws + 8388608 + 65536);              // 32 KB
    unsigned* done   = (unsigned*)(ws + 8388608 + 98304);              // 4 B

    k_prep<<<N_ROWS / 16, 256, 0, stream>>>(imgs, caps, fimgs, fcaps,
                                            diag, rowmax, colmax, done, out);
    k_gemm<<<dim3(64, 128), 256, 0, stream>>>(fimgs, fcaps, rowmax, colmax,
                                              diag, done, out);
}

// Round 13
// 155.361 us; speedup vs baseline: 4.8369x; 4.8369x over previous
//
#include <hip/hip_runtime.h>

#define N_ROWS 8192
#define DIM    512

typedef __attribute__((ext_vector_type(4))) float frag_cd;      // 4 fp32 acc
typedef __attribute__((ext_vector_type(2))) long long v2ll;     // 16B = 2 fp8 fragments

// fp32 -> OCP e4m3fn, RNE, FTZ below 2^-6 (negligible for N(0,1) data).
__device__ __forceinline__ unsigned f2fp8(float x) {
    float a = fabsf(x);
    unsigned s = (__float_as_uint(x) >> 31) << 7;
    if (a < 0.015625f) return s;                 // FTZ subnormals
    a = fminf(a, 448.f);                         // e4m3fn max
    unsigned u = __float_as_uint(a);
    u += 0x7FFFFu + ((u >> 20) & 1u);            // RNE round mantissa to 3 bits
    unsigned exp = (u >> 23) - 120u;             // fp32exp-127+7 in [1,15]
    unsigned mant = (u >> 20) & 7u;
    return s | (exp << 3) | mant;
}
__device__ __forceinline__ unsigned pack4fp8(float4 v) {
    return f2fp8(v.x) | (f2fp8(v.y) << 8) | (f2fp8(v.z) << 16) | (f2fp8(v.w) << 24);
}
// order-preserving f32 -> u32 key (monotone), so atomicMax(uint) == float max
__device__ __forceinline__ unsigned enc_f32(float f) {
    unsigned u = __float_as_uint(f);
    return (u & 0x80000000u) ? ~u : (u | 0x80000000u);
}
__device__ __forceinline__ float dec_f32(unsigned k) {
    return __uint_as_float((k & 0x80000000u) ? (k & 0x7FFFFFFFu) : ~k);
}

// ---- TILED fp8 layout (round-8/9/10 verified exact) ----
// Pair-chunk (cr, kp) = 16 rows x 64 K-cols = 1 KB, 64 units of 16B:
// unit u = cg*16+rin = [kc-even 8B | kc-odd 8B], cols kp*64+par*32+cg*8.
// Byte addr = cr*8192 + kp*1024 + u*16.

// ---- kernel 1: convert + diag + init (round-10 verbatim) ----
__global__ __launch_bounds__(256) void k_prep(const float* __restrict__ imgs,
                                              const float* __restrict__ caps,
                                              unsigned char* __restrict__ fimgs,
                                              unsigned char* __restrict__ fcaps,
                                              float* __restrict__ diag,
                                              unsigned* __restrict__ rowmax,
                                              unsigned* __restrict__ colmax,
                                              float* __restrict__ out) {
    const int cr = blockIdx.x;            // 0..511
    const int t  = threadIdx.x;
    const int w = t >> 6, l = t & 63;
    const int kp = l >> 3, cg = l & 3, par = (l >> 2) & 1;
    if (cr == 0 && t == 0) out[0] = 0.f;  // zero accumulator for k_final's atomics
    const size_t ubase = (size_t)cr * 8192 + kp * 1024 + cg * 256 + par * 8;
    float ps[4];
    #pragma unroll
    for (int i = 0; i < 4; ++i) {
        const int row = w + 4 * i;                 // 0..15
        const float* ar = imgs + ((size_t)cr * 16 + row) * DIM + l * 8;
        const float* br = caps + ((size_t)cr * 16 + row) * DIM + l * 8;
        float4 a0 = *(const float4*)ar, a1 = *(const float4*)(ar + 4);
        float4 b0 = *(const float4*)br, b1 = *(const float4*)(br + 4);
        uint2 oa, ob;
        oa.x = pack4fp8(a0); oa.y = pack4fp8(a1);
        ob.x = pack4fp8(b0); ob.y = pack4fp8(b1);
        *(uint2*)(fimgs + ubase + row * 16) = oa;
        *(uint2*)(fcaps + ubase + row * 16) = ob;
        ps[i] = a0.x * b0.x + a0.y * b0.y + a0.z * b0.z + a0.w * b0.w
              + a1.x * b1.x + a1.y * b1.y + a1.z * b1.z + a1.w * b1.w;
    }
    #pragma unroll
    for (int i = 0; i < 4; ++i) {
        float s = ps[i];
        #pragma unroll
        for (int m = 1; m < 64; m <<= 1) s += __shfl_xor(s, m, 64);
        if (l == 0) {
            const int r = cr * 16 + w + 4 * i;
            diag[r] = s; rowmax[r] = 0u; colmax[r] = 0u;
        }
    }
}

// ---- kernel 2: fused fp8 NT-GEMM + diag flip + row/col max ----
// Round-10 body verbatim; NEW: XCD-aware job swizzle. Flat job id f:
//   xcd = f&7, g = f>>3, j = (f&7)*8 + (g&7), i = g>>3
// Each XCD owns 8 j0-panels (512 KB of B, L2-resident) and sweeps i with
// 8-job temporal A-panel reuse. Dispatch mapping is a perf heuristic only.
__global__ __launch_bounds__(256, 6) void k_gemm(const unsigned char* __restrict__ A,
                                                 const unsigned char* __restrict__ B,
                                                 unsigned* __restrict__ rowmax,
                                                 unsigned* __restrict__ colmax) {
    __shared__ unsigned char sA[2][4096];   // 4 chunk slots x 1 KB
    __shared__ unsigned char sB[2][8192];   // 8 chunk slots x 1 KB
    const int tid = threadIdx.x;
    const int w = tid >> 6, lane = tid & 63;
    // XCD-aware swizzle of the flat job id
    const int f = (int)blockIdx.x;
    const int jb = (f & 7) * 8 + ((f >> 3) & 7);   // 0..63
    const int ib = f >> 6;                          // 0..127
    const int j0 = jb << 7, i0 = ib << 6;
    const int q = lane >> 4, l15 = lane & 15;
    const int wr = (w & 1) << 5, wc = (w >> 1) << 6;   // wave tile origin

    const unsigned char* Ab = A + (size_t)(i0 >> 4) * 8192 + lane * 16;
    const unsigned char* Bb = B + (size_t)(j0 >> 4) * 8192 + lane * 16;

    frag_cd acc[2][4] = {};

    auto stage = [&](int bi, int kp) {
        __builtin_amdgcn_global_load_lds(
            (const __attribute__((address_space(1))) unsigned int*)(Ab + (size_t)w * 8192 + kp * 1024),
            (__attribute__((address_space(3))) unsigned int*)(&sA[bi][(w << 10) + (lane << 4)]), 16, 0, 0);
        #pragma unroll
        for (int j = 0; j < 2; ++j) {
            const int s = 2 * w + j;
            __builtin_amdgcn_global_load_lds(
                (const __attribute__((address_space(1))) unsigned int*)(Bb + (size_t)s * 8192 + kp * 1024),
                (__attribute__((address_space(3))) unsigned int*)(&sB[bi][(s << 10) + (lane << 4)]), 16, 0, 0);
        }
    };

    stage(0, 0);
    __syncthreads();   // cold drain (once)

    const int u16 = ((q << 4) + l15) << 4;   // fragment byte offset in chunk

    #pragma unroll
    for (int kp = 0; kp < 8; ++kp) {
        const int cur = kp & 1, nxt = cur ^ 1;
        if (kp < 7) stage(nxt, kp + 1);   // in flight during compute below

        v2ll af[2], bfr[4];
        #pragma unroll
        for (int r = 0; r < 2; ++r)   // A chunk = (w&1)*2 + r
            af[r] = *(const v2ll*)(&sA[cur][((((w & 1) << 1) + r) << 10) + u16]);
        #pragma unroll
        for (int c = 0; c < 4; ++c)   // B chunk = (w>>1)*4 + c
            bfr[c] = *(const v2ll*)(&sB[cur][((((w >> 1) << 2) + c) << 10) + u16]);
        #pragma unroll
        for (int r = 0; r < 2; ++r)
            #pragma unroll
            for (int c = 0; c < 4; ++c)
                acc[r][c] = __builtin_amdgcn_mfma_f32_16x16x32_fp8_fp8(af[r][0], bfr[c][0], acc[r][c], 0, 0, 0);
        #pragma unroll
        for (int r = 0; r < 2; ++r)
            #pragma unroll
            for (int c = 0; c < 4; ++c)
                acc[r][c] = __builtin_amdgcn_mfma_f32_16x16x32_fp8_fp8(af[r][1], bfr[c][1], acc[r][c], 0, 0, 0);

        __syncthreads();
    }

    // ---- epilogue: diagonal flip + row/col max + device atomics ----
    // C/D layout: col = lane&15, row = (lane>>4)*4 + reg (dtype-independent)
    const bool dblk = ((i0 >> 7) == jb);
    #pragma unroll
    for (int r = 0; r < 2; ++r)
        #pragma unroll
        for (int c = 0; c < 4; ++c)
            #pragma unroll
            for (int g = 0; g < 4; ++g) {
                float fv = acc[r][c][g];
                const int gi = wr + (r << 4) + (q << 2) + g;          // row in block
                const int gj = wc + (c << 4) + l15;                   // col in block
                if (dblk && (i0 + gi) == (j0 + gj)) fv = -fv;         // s[i][i] = -diag
                acc[r][c][g] = fv;
            }

    #pragma unroll
    for (int r = 0; r < 2; ++r)
        #pragma unroll
        for (int g = 0; g < 4; ++g) {
            float m = fmaxf(fmaxf(acc[r][0][g], acc[r][1][g]),
                            fmaxf(acc[r][2][g], acc[r][3][g]));
            m = fmaxf(m, __shfl_xor(m, 1, 64));
            m = fmaxf(m, __shfl_xor(m, 2, 64));
            m = fmaxf(m, __shfl_xor(m, 4, 64));
            m = fmaxf(m, __shfl_xor(m, 8, 64));
            if (l15 == 0)
                atomicMax(&rowmax[i0 + wr + (r << 4) + (q << 2) + g], enc_f32(m));
        }
    #pragma unroll
    for (int c = 0; c < 4; ++c) {
        float m = acc[0][c][0];
        #pragma unroll
        for (int r = 0; r < 2; ++r)
            #pragma unroll
            for (int g = 0; g < 4; ++g) m = fmaxf(m, acc[r][c][g]);
        m = fmaxf(m, __shfl_xor(m, 16, 64));
        m = fmaxf(m, __shfl_xor(m, 32, 64));
        if (q == 0)
            atomicMax(&colmax[j0 + wc + (c << 4) + l15], enc_f32(m));
    }
}

// ---- kernel 3: hinge terms, 32 blocks + one atomicAdd per block ----
__global__ __launch_bounds__(256) void k_final(const unsigned* __restrict__ rowmax,
                                               const unsigned* __restrict__ colmax,
                                               const float* __restrict__ diag,
                                               float* __restrict__ out) {
    const int idx = blockIdx.x * 256 + threadIdx.x;
    const float d = diag[idx];
    float s = fmaxf(dec_f32(rowmax[idx]) + 0.2f - d, 0.f)    // neg_img
            + fmaxf(dec_f32(colmax[idx]) + 0.2f - d, 0.f);   // neg_cap
    #pragma unroll
    for (int m = 1; m < 64; m <<= 1) s += __shfl_xor(s, m, 64);
    __shared__ float red[4];
    if ((threadIdx.x & 63) == 0) red[threadIdx.x >> 6] = s;
    __syncthreads();
    if (threadIdx.x == 0)
        atomicAdd(out, red[0] + red[1] + red[2] + red[3]);
}

extern "C" void kernel_launch(void* const* d_in, const int* in_sizes, int n_in,
                              void* d_out, int out_size, void* d_ws, size_t ws_size,
                              hipStream_t stream) {
    const float* imgs = (const float*)d_in[0];
    const float* caps = (const float*)d_in[1];
    float* out = (float*)d_out;

    char* ws = (char*)d_ws;
    unsigned char* fimgs = (unsigned char*)ws;                         // 4 MB tiled fp8
    unsigned char* fcaps = (unsigned char*)(ws + 4194304);             // 4 MB tiled fp8
    float*    diag   = (float*)   (ws + 8388608);                      // 32 KB
    unsigned* rowmax = (unsigned*)(ws + 8388608 + 32768);              // 32 KB
    unsigned* colmax = (unsigned*)(ws + 8388608 + 65536);              // 32 KB

    k_prep<<<N_ROWS / 16, 256, 0, stream>>>(imgs, caps, fimgs, fcaps,
                                            diag, rowmax, colmax, out);
    k_gemm<<<8192, 256, 0, stream>>>(fimgs, fcaps, rowmax, colmax);
    k_final<<<N_ROWS / 256, 256, 0, stream>>>(rowmax, colmax, diag, out);
}